// Round 1
// baseline (2246.692 us; speedup 1.0000x reference)
//
#include <hip/hip_runtime.h>

#define NU 100000
#define NI 50000
#define NE 1000000
#define NB 16384

// ---- degree count ----
__global__ void deg_kernel(const int* __restrict__ ei, float* du, float* di) {
    int e = blockIdx.x * blockDim.x + threadIdx.x;
    if (e >= NE) return;
    atomicAdd(&du[ei[e]], 1.0f);
    atomicAdd(&di[ei[NE + e]], 1.0f);
}

// ---- reciprocal sqrt degree ----
__global__ void rsd_kernel(const float* __restrict__ du, const float* __restrict__ di,
                           float* rsd_u, float* rsd_i) {
    int i = blockIdx.x * blockDim.x + threadIdx.x;
    if (i < NU) {
        float d = du[i];
        rsd_u[i] = d > 0.f ? 1.0f / sqrtf(d) : 0.f;
    } else if (i < NU + NI) {
        int j = i - NU;
        float d = di[j];
        rsd_i[j] = d > 0.f ? 1.0f / sqrtf(d) : 0.f;
    }
}

// ---- per-node sum of neighbor rsd (for the b1 term) ----
__global__ void tsum_kernel(const int* __restrict__ ei, const float* __restrict__ rsd_u,
                            const float* __restrict__ rsd_i, float* tsum_u, float* tsum_i) {
    int e = blockIdx.x * blockDim.x + threadIdx.x;
    if (e >= NE) return;
    int s = ei[e], d = ei[NE + e];
    atomicAdd(&tsum_u[d], rsd_u[s]);
    atomicAdd(&tsum_i[s], rsd_i[d]);
}

// ---- edge scatter: one wave (64 lanes) per edge, lane = dim ----
// st_i[d][0:64] = sum u[src] ; st_i[d][64:128] = sum rsd_u[src]*u[src]
// st_u[s][0:64] = sum i[dst] ; st_u[s][64:128] = sum rsd_i[dst]*i[dst]
__global__ void scatter_kernel(const float* __restrict__ in_u, const float* __restrict__ in_i,
                               const int* __restrict__ ei,
                               const float* __restrict__ rsd_u, const float* __restrict__ rsd_i,
                               float* __restrict__ st_i, float* __restrict__ st_u) {
    int wv = (blockIdx.x * blockDim.x + threadIdx.x) >> 6;
    int lane = threadIdx.x & 63;
    if (wv >= NE) return;
    int s = ei[wv], d = ei[NE + wv];
    float uval = in_u[s * 64 + lane];
    float ival = in_i[d * 64 + lane];
    float su = rsd_u[s], si = rsd_i[d];
    atomicAdd(&st_i[d * 128 + lane], uval);
    atomicAdd(&st_i[d * 128 + 64 + lane], uval * su);
    atomicAdd(&st_u[s * 128 + lane], ival);
    atomicAdd(&st_u[s * 128 + 64 + lane], ival * si);
}

// ---- per-node transform + epilogue: one wave per node, lane = out dim ----
// out[n] = L2norm(leaky( (rsd[n]*T[n])@W1 + rsd[n]*tsum[n]*b1 + (x[n]*S[n])@W2 + deg[n]*b2 ))
__global__ __launch_bounds__(256) void transform_kernel(
        int N, const float* __restrict__ x_in, const float* __restrict__ st,
        const float* __restrict__ rsd, const float* __restrict__ tsum,
        const float* __restrict__ deg,
        const float* __restrict__ W1, const float* __restrict__ b1,
        const float* __restrict__ W2, const float* __restrict__ b2,
        float* __restrict__ out) {
    __shared__ float w1s[64 * 64];
    __shared__ float w2s[64 * 64];
    __shared__ float acs[4][128];
    int tid = threadIdx.x;
    #pragma unroll
    for (int t = 0; t < 16; ++t) {
        w1s[t * 256 + tid] = W1[t * 256 + tid];
        w2s[t * 256 + tid] = W2[t * 256 + tid];
    }
    int wv = tid >> 6, lane = tid & 63;
    int n = blockIdx.x * 4 + wv;
    bool act = n < N;
    float aval = 0.f, cval = 0.f, rs = 0.f, ts = 0.f, dg = 0.f;
    if (act) {
        rs = rsd[n];
        ts = tsum[n];
        dg = deg[n];
        aval = rs * st[(size_t)n * 128 + 64 + lane];        // scaled T
        cval = x_in[(size_t)n * 64 + lane] * st[(size_t)n * 128 + lane]; // x * S
    }
    acs[wv][lane] = aval;
    acs[wv][64 + lane] = cval;
    __syncthreads();
    if (act) {
        float acc = 0.f;
        #pragma unroll 8
        for (int k = 0; k < 64; ++k) {
            acc += acs[wv][k] * w1s[k * 64 + lane];
            acc += acs[wv][64 + k] * w2s[k * 64 + lane];
        }
        acc += rs * ts * b1[lane] + dg * b2[lane];
        float h = acc >= 0.f ? acc : 0.2f * acc;
        float ss = h * h;
        #pragma unroll
        for (int off = 32; off > 0; off >>= 1) ss += __shfl_xor(ss, off);
        float nrm = sqrtf(ss);
        out[(size_t)n * 64 + lane] = h / fmaxf(nrm, 1e-12f);
    }
}

// ---- final gather of concatenated embeddings ----
__global__ void gather_kernel(const float* __restrict__ ue, const float* __restrict__ u1,
                              const float* __restrict__ u2, const float* __restrict__ ie,
                              const float* __restrict__ i1, const float* __restrict__ i2,
                              const int* __restrict__ users, const int* __restrict__ pos,
                              const int* __restrict__ neg, float* __restrict__ out) {
    int idx = blockIdx.x * blockDim.x + threadIdx.x;
    if (idx >= 3 * NB * 192) return;
    int which = idx / (NB * 192);
    int rem = idx - which * (NB * 192);
    int b = rem / 192, c = rem - b * 192;
    int seg = c >> 6, cc = c & 63;
    int row;
    const float* srcarr;
    if (which == 0) {
        row = users[b];
        srcarr = (seg == 0) ? ue : (seg == 1 ? u1 : u2);
    } else {
        row = (which == 1) ? pos[b] : neg[b];
        srcarr = (seg == 0) ? ie : (seg == 1 ? i1 : i2);
    }
    out[idx] = srcarr[(size_t)row * 64 + cc];
}

extern "C" void kernel_launch(void* const* d_in, const int* in_sizes, int n_in,
                              void* d_out, int out_size, void* d_ws, size_t ws_size,
                              hipStream_t stream) {
    const float* user_emb = (const float*)d_in[0];
    const float* item_emb = (const float*)d_in[1];
    const float* W1_0 = (const float*)d_in[2];
    const float* b1_0 = (const float*)d_in[3];
    const float* W2_0 = (const float*)d_in[4];
    const float* b2_0 = (const float*)d_in[5];
    const float* W1_1 = (const float*)d_in[6];
    const float* b1_1 = (const float*)d_in[7];
    const float* W2_1 = (const float*)d_in[8];
    const float* b2_1 = (const float*)d_in[9];
    const int* ei = (const int*)d_in[10];
    const int* users = (const int*)d_in[11];
    const int* pos = (const int*)d_in[12];
    const int* neg = (const int*)d_in[13];
    float* out = (float*)d_out;

    float* p = (float*)d_ws;
    float* du = p;      p += NU;
    float* di = p;      p += NI;
    float* tsum_u = p;  p += NI;   // at items: sum over in-edges of rsd_u[src]
    float* tsum_i = p;  p += NU;   // at users: sum over edges of rsd_i[dst]
    float* rsd_u = p;   p += NU;
    float* rsd_i = p;   p += NI;
    float* st_i = p;    p += (size_t)NI * 128;
    float* st_u = p;    p += (size_t)NU * 128;
    float* u1 = p;      p += (size_t)NU * 64;
    float* u2 = p;      p += (size_t)NU * 64;
    float* i1 = p;      p += (size_t)NI * 64;
    float* i2 = p;      p += (size_t)NI * 64;

    // zero accumulators (ws is poisoned before every call)
    hipMemsetAsync(du, 0, (size_t)(NU + NI + NI + NU) * sizeof(float), stream);

    deg_kernel<<<(NE + 255) / 256, 256, 0, stream>>>(ei, du, di);
    rsd_kernel<<<(NU + NI + 255) / 256, 256, 0, stream>>>(du, di, rsd_u, rsd_i);
    tsum_kernel<<<(NE + 255) / 256, 256, 0, stream>>>(ei, rsd_u, rsd_i, tsum_u, tsum_i);

    // ---- layer 0 ----
    hipMemsetAsync(st_i, 0, (size_t)(NI + NU) * 128 * sizeof(float), stream);
    scatter_kernel<<<NE / 4, 256, 0, stream>>>(user_emb, item_emb, ei, rsd_u, rsd_i, st_i, st_u);
    transform_kernel<<<(NI + 3) / 4, 256, 0, stream>>>(NI, item_emb, st_i, rsd_i, tsum_u, di,
                                                       W1_0, b1_0, W2_0, b2_0, i1);
    transform_kernel<<<(NU + 3) / 4, 256, 0, stream>>>(NU, user_emb, st_u, rsd_u, tsum_i, du,
                                                       W1_0, b1_0, W2_0, b2_0, u1);

    // ---- layer 1 ----
    hipMemsetAsync(st_i, 0, (size_t)(NI + NU) * 128 * sizeof(float), stream);
    scatter_kernel<<<NE / 4, 256, 0, stream>>>(u1, i1, ei, rsd_u, rsd_i, st_i, st_u);
    transform_kernel<<<(NI + 3) / 4, 256, 0, stream>>>(NI, i1, st_i, rsd_i, tsum_u, di,
                                                       W1_1, b1_1, W2_1, b2_1, i2);
    transform_kernel<<<(NU + 3) / 4, 256, 0, stream>>>(NU, u1, st_u, rsd_u, tsum_i, du,
                                                       W1_1, b1_1, W2_1, b2_1, u2);

    // ---- final gather ----
    gather_kernel<<<(3 * NB * 192 + 255) / 256, 256, 0, stream>>>(
        user_emb, u1, u2, item_emb, i1, i2, users, pos, neg, out);
}

// Round 2
// 1273.570 us; speedup vs baseline: 1.7641x; 1.7641x over previous
//
#include <hip/hip_runtime.h>

#define NU 100000
#define NI 50000
#define NE 1000000
#define NB 16384

// ---- degree count (int atomics) ----
__global__ void deg_kernel(const int* __restrict__ ei, int* du, int* di) {
    int e = blockIdx.x * blockDim.x + threadIdx.x;
    if (e >= NE) return;
    atomicAdd(&du[ei[e]], 1);
    atomicAdd(&di[ei[NE + e]], 1);
}

// ---- reciprocal sqrt degree ----
__global__ void rsd_kernel(const int* __restrict__ du, const int* __restrict__ di,
                           float* rsd_u, float* rsd_i) {
    int i = blockIdx.x * blockDim.x + threadIdx.x;
    if (i < NU) {
        int d = du[i];
        rsd_u[i] = d > 0 ? 1.0f / sqrtf((float)d) : 0.f;
    } else if (i < NU + NI) {
        int j = i - NU;
        int d = di[j];
        rsd_i[j] = d > 0 ? 1.0f / sqrtf((float)d) : 0.f;
    }
}

// ---- exclusive prefix scan (block 0: users, block 1: items) ----
__global__ __launch_bounds__(1024) void scan_kernel(
        const int* __restrict__ degu, const int* __restrict__ degi,
        int* rpu, int* rpi, int* curu, int* curi) {
    const int N = (blockIdx.x == 0) ? NU : NI;
    const int* deg = (blockIdx.x == 0) ? degu : degi;
    int* rp  = (blockIdx.x == 0) ? rpu : rpi;
    int* cur = (blockIdx.x == 0) ? curu : curi;
    int tid = threadIdx.x;
    int C = (N + 1023) / 1024;
    int b0 = tid * C;
    int b1 = min(b0 + C, N);
    int s = 0;
    for (int i = b0; i < b1; ++i) s += deg[i];
    __shared__ int sh[1024];
    sh[tid] = s;
    __syncthreads();
    for (int off = 1; off < 1024; off <<= 1) {
        int v = (tid >= off) ? sh[tid - off] : 0;
        __syncthreads();
        sh[tid] += v;
        __syncthreads();
    }
    int run = (tid > 0) ? sh[tid - 1] : 0;
    for (int i = b0; i < b1; ++i) {
        rp[i] = run; cur[i] = run;
        run += deg[i];
    }
    if (tid == 1023) rp[N] = sh[1023];
}

// ---- CSR fill: 2M int atomics instead of 256M float atomics ----
__global__ void fill_csr_kernel(const int* __restrict__ ei,
                                int* __restrict__ curu, int* __restrict__ curi,
                                int* __restrict__ csr_u, int* __restrict__ csr_i) {
    int e = blockIdx.x * blockDim.x + threadIdx.x;
    if (e >= NE) return;
    int s = ei[e], d = ei[NE + e];
    int si = atomicAdd(&curi[d], 1);
    csr_i[si] = s;
    int su = atomicAdd(&curu[s], 1);
    csr_u[su] = d;
}

// ---- fused gather + transform + epilogue: one wave per node ----
// out[n] = L2norm(leaky( (rsd[n]*ss)@W1 + rsd[n]*sw*b1 + (x[n]*sp)@W2 + deg*b2 ))
// where over neighbors idx: sp=Σ emb[idx], ss=Σ rsd_o[idx]*emb[idx], sw=Σ rsd_o[idx]
__global__ __launch_bounds__(256) void gt_kernel(
        int N, const float* __restrict__ x_in, const float* __restrict__ emb_other,
        const int* __restrict__ rowptr, const int* __restrict__ csr,
        const float* __restrict__ rsd_own, const float* __restrict__ rsd_other,
        const float* __restrict__ W1, const float* __restrict__ b1,
        const float* __restrict__ W2, const float* __restrict__ b2,
        float* __restrict__ out) {
    __shared__ float w1s[64 * 64];
    __shared__ float w2s[64 * 64];
    __shared__ float acs[4][128];
    int tid = threadIdx.x;
    #pragma unroll
    for (int t = 0; t < 16; ++t) {
        w1s[t * 256 + tid] = W1[t * 256 + tid];
        w2s[t * 256 + tid] = W2[t * 256 + tid];
    }
    int wv = tid >> 6, lane = tid & 63;
    int n = blockIdx.x * 4 + wv;
    bool act = n < N;
    float sp = 0.f, ss = 0.f, sw = 0.f, rs = 0.f, dgf = 0.f;
    if (act) {
        int beg = rowptr[n], end = rowptr[n + 1];
        dgf = (float)(end - beg);
        rs = rsd_own[n];
        int j = beg;
        // 2-neighbor unroll for memory-level parallelism
        for (; j + 1 < end; j += 2) {
            int i0 = csr[j], i1 = csr[j + 1];
            float w0 = rsd_other[i0], w1v = rsd_other[i1];
            float v0 = emb_other[(size_t)i0 * 64 + lane];
            float v1 = emb_other[(size_t)i1 * 64 + lane];
            sp += v0 + v1;
            ss += w0 * v0 + w1v * v1;
            sw += w0 + w1v;
        }
        if (j < end) {
            int i0 = csr[j];
            float w0 = rsd_other[i0];
            float v0 = emb_other[(size_t)i0 * 64 + lane];
            sp += v0; ss += w0 * v0; sw += w0;
        }
    }
    float a = rs * ss;
    float c = act ? x_in[(size_t)n * 64 + lane] * sp : 0.f;
    acs[wv][lane] = a;
    acs[wv][64 + lane] = c;
    __syncthreads();
    if (act) {
        float acc = 0.f;
        #pragma unroll 8
        for (int k = 0; k < 64; ++k) {
            acc += acs[wv][k] * w1s[k * 64 + lane];
            acc += acs[wv][64 + k] * w2s[k * 64 + lane];
        }
        acc += rs * sw * b1[lane] + dgf * b2[lane];
        float h = acc >= 0.f ? acc : 0.2f * acc;
        float nsq = h * h;
        #pragma unroll
        for (int off = 32; off > 0; off >>= 1) nsq += __shfl_xor(nsq, off);
        float nrm = sqrtf(nsq);
        out[(size_t)n * 64 + lane] = h / fmaxf(nrm, 1e-12f);
    }
}

// ---- final gather of concatenated embeddings ----
__global__ void gather_kernel(const float* __restrict__ ue, const float* __restrict__ u1,
                              const float* __restrict__ u2, const float* __restrict__ ie,
                              const float* __restrict__ i1, const float* __restrict__ i2,
                              const int* __restrict__ users, const int* __restrict__ pos,
                              const int* __restrict__ neg, float* __restrict__ out) {
    int idx = blockIdx.x * blockDim.x + threadIdx.x;
    if (idx >= 3 * NB * 192) return;
    int which = idx / (NB * 192);
    int rem = idx - which * (NB * 192);
    int b = rem / 192, c = rem - b * 192;
    int seg = c >> 6, cc = c & 63;
    int row;
    const float* srcarr;
    if (which == 0) {
        row = users[b];
        srcarr = (seg == 0) ? ue : (seg == 1 ? u1 : u2);
    } else {
        row = (which == 1) ? pos[b] : neg[b];
        srcarr = (seg == 0) ? ie : (seg == 1 ? i1 : i2);
    }
    out[idx] = srcarr[(size_t)row * 64 + cc];
}

extern "C" void kernel_launch(void* const* d_in, const int* in_sizes, int n_in,
                              void* d_out, int out_size, void* d_ws, size_t ws_size,
                              hipStream_t stream) {
    const float* user_emb = (const float*)d_in[0];
    const float* item_emb = (const float*)d_in[1];
    const float* W1_0 = (const float*)d_in[2];
    const float* b1_0 = (const float*)d_in[3];
    const float* W2_0 = (const float*)d_in[4];
    const float* b2_0 = (const float*)d_in[5];
    const float* W1_1 = (const float*)d_in[6];
    const float* b1_1 = (const float*)d_in[7];
    const float* W2_1 = (const float*)d_in[8];
    const float* b2_1 = (const float*)d_in[9];
    const int* ei = (const int*)d_in[10];
    const int* users = (const int*)d_in[11];
    const int* pos = (const int*)d_in[12];
    const int* neg = (const int*)d_in[13];
    float* out = (float*)d_out;

    char* p = (char*)d_ws;
    int* du = (int*)p;        p += NU * 4;
    int* di = (int*)p;        p += NI * 4;
    float* rsd_u = (float*)p; p += NU * 4;
    float* rsd_i = (float*)p; p += NI * 4;
    int* rp_u = (int*)p;      p += (NU + 1) * 4;
    int* rp_i = (int*)p;      p += (NI + 1) * 4;
    int* cur_u = (int*)p;     p += NU * 4;
    int* cur_i = (int*)p;     p += NI * 4;
    int* csr_u = (int*)p;     p += (size_t)NE * 4;
    int* csr_i = (int*)p;     p += (size_t)NE * 4;
    float* u1 = (float*)p;    p += (size_t)NU * 64 * 4;
    float* u2 = (float*)p;    p += (size_t)NU * 64 * 4;
    float* i1 = (float*)p;    p += (size_t)NI * 64 * 4;
    float* i2 = (float*)p;    p += (size_t)NI * 64 * 4;

    // zero the degree counters (ws is re-poisoned before every call)
    hipMemsetAsync(du, 0, (size_t)(NU + NI) * sizeof(int), stream);

    deg_kernel<<<(NE + 255) / 256, 256, 0, stream>>>(ei, du, di);
    rsd_kernel<<<(NU + NI + 255) / 256, 256, 0, stream>>>(du, di, rsd_u, rsd_i);
    scan_kernel<<<2, 1024, 0, stream>>>(du, di, rp_u, rp_i, cur_u, cur_i);
    fill_csr_kernel<<<(NE + 255) / 256, 256, 0, stream>>>(ei, cur_u, cur_i, csr_u, csr_i);

    // ---- layer 0 ----
    gt_kernel<<<(NI + 3) / 4, 256, 0, stream>>>(NI, item_emb, user_emb, rp_i, csr_i,
                                                rsd_i, rsd_u, W1_0, b1_0, W2_0, b2_0, i1);
    gt_kernel<<<(NU + 3) / 4, 256, 0, stream>>>(NU, user_emb, item_emb, rp_u, csr_u,
                                                rsd_u, rsd_i, W1_0, b1_0, W2_0, b2_0, u1);

    // ---- layer 1 ----
    gt_kernel<<<(NI + 3) / 4, 256, 0, stream>>>(NI, i1, u1, rp_i, csr_i,
                                                rsd_i, rsd_u, W1_1, b1_1, W2_1, b2_1, i2);
    gt_kernel<<<(NU + 3) / 4, 256, 0, stream>>>(NU, u1, i1, rp_u, csr_u,
                                                rsd_u, rsd_i, W1_1, b1_1, W2_1, b2_1, u2);

    // ---- final gather ----
    gather_kernel<<<(3 * NB * 192 + 255) / 256, 256, 0, stream>>>(
        user_emb, u1, u2, item_emb, i1, i2, users, pos, neg, out);
}

// Round 3
// 709.467 us; speedup vs baseline: 3.1667x; 1.7951x over previous
//
#include <hip/hip_runtime.h>

#define NU 100000
#define NI 50000
#define NE 1000000
#define NB 16384

#define UB ((NU + 1023) / 1024)   // 98 user scan blocks
#define IB ((NI + 1023) / 1024)   // 49 item scan blocks

// ---- degree count (int atomics) ----
__global__ void deg_kernel(const int* __restrict__ ei, int* du, int* di) {
    int e = blockIdx.x * blockDim.x + threadIdx.x;
    if (e >= NE) return;
    atomicAdd(&du[ei[e]], 1);
    atomicAdd(&di[ei[NE + e]], 1);
}

// ---- scan pass 1: per-block partial sums (+ fused rsd computation) ----
__global__ __launch_bounds__(1024) void scan1_kernel(
        const int* __restrict__ du, const int* __restrict__ di,
        int* __restrict__ psum, float* __restrict__ rsd_u, float* __restrict__ rsd_i) {
    int b = blockIdx.x, tid = threadIdx.x;
    int v = 0;
    if (b < UB) {
        int i = b * 1024 + tid;
        if (i < NU) {
            int d = du[i]; v = d;
            rsd_u[i] = d > 0 ? 1.0f / sqrtf((float)d) : 0.f;
        }
    } else {
        int i = (b - UB) * 1024 + tid;
        if (i < NI) {
            int d = di[i]; v = d;
            rsd_i[i] = d > 0 ? 1.0f / sqrtf((float)d) : 0.f;
        }
    }
    int s = v;
    #pragma unroll
    for (int off = 32; off > 0; off >>= 1) s += __shfl_xor(s, off);
    __shared__ int ws[16];
    if ((tid & 63) == 0) ws[tid >> 6] = s;
    __syncthreads();
    if (tid == 0) {
        int t = 0;
        #pragma unroll
        for (int w = 0; w < 16; ++w) t += ws[w];
        psum[b] = t;
    }
}

// ---- scan pass 2: exclusive scan of block partials (per segment) ----
__global__ __launch_bounds__(128) void scan2_kernel(int* __restrict__ psum) {
    int base = (blockIdx.x == 0) ? 0 : UB;
    int n = (blockIdx.x == 0) ? UB : IB;
    int tid = threadIdx.x;
    __shared__ int sh[128];
    int v = (tid < n) ? psum[base + tid] : 0;
    sh[tid] = v;
    __syncthreads();
    for (int off = 1; off < 128; off <<= 1) {
        int t = (tid >= off) ? sh[tid - off] : 0;
        __syncthreads();
        sh[tid] += t;
        __syncthreads();
    }
    if (tid < n) psum[base + tid] = sh[tid] - v;  // exclusive
}

// ---- scan pass 3: block-local exclusive scan + offset -> rowptr, cursor ----
__global__ __launch_bounds__(1024) void scan3_kernel(
        const int* __restrict__ du, const int* __restrict__ di,
        const int* __restrict__ psum,
        int* __restrict__ rp_u, int* __restrict__ rp_i,
        int* __restrict__ cur_u, int* __restrict__ cur_i) {
    int b = blockIdx.x, tid = threadIdx.x;
    const int* deg; int* rp; int* cur; int N; int i0;
    if (b < UB) { deg = du; rp = rp_u; cur = cur_u; N = NU; i0 = b * 1024; }
    else        { deg = di; rp = rp_i; cur = cur_i; N = NI; i0 = (b - UB) * 1024; }
    int i = i0 + tid;
    int v = (i < N) ? deg[i] : 0;
    __shared__ int sh[1024];
    sh[tid] = v;
    __syncthreads();
    for (int off = 1; off < 1024; off <<= 1) {
        int t = (tid >= off) ? sh[tid - off] : 0;
        __syncthreads();
        sh[tid] += t;
        __syncthreads();
    }
    int excl = sh[tid] - v + psum[b];
    if (i < N) { rp[i] = excl; cur[i] = excl; }
    if (b == 0 && tid == 0) { rp_u[NU] = NE; rp_i[NI] = NE; }
}

// ---- CSR fill: 2M int atomics ----
__global__ void fill_csr_kernel(const int* __restrict__ ei,
                                int* __restrict__ curu, int* __restrict__ curi,
                                int* __restrict__ csr_u, int* __restrict__ csr_i) {
    int e = blockIdx.x * blockDim.x + threadIdx.x;
    if (e >= NE) return;
    int s = ei[e], d = ei[NE + e];
    int si = atomicAdd(&curi[d], 1);
    csr_i[si] = s;
    int su = atomicAdd(&curu[s], 1);
    csr_u[su] = d;
}

// ---- fused gather + transform + epilogue for BOTH directions ----
// node id n in [0, NI+NU): n<NI -> item node, else user node n-NI
// out[n] = L2norm(leaky( (rsd*ss)@W1 + rsd*sw*b1 + (x*sp)@W2 + deg*b2 ))
__global__ __launch_bounds__(512) void gt_fused_kernel(
        const float* __restrict__ xu, const float* __restrict__ xi,
        const int* __restrict__ rpu, const int* __restrict__ rpi,
        const int* __restrict__ csru, const int* __restrict__ csri,
        const float* __restrict__ rsdu, const float* __restrict__ rsdi,
        const float* __restrict__ W1, const float* __restrict__ b1,
        const float* __restrict__ W2, const float* __restrict__ b2,
        float* __restrict__ outu, float* __restrict__ outi) {
    __shared__ float w1s[64 * 64];
    __shared__ float w2s[64 * 64];
    __shared__ float acs[8][128];
    int tid = threadIdx.x;
    #pragma unroll
    for (int t = 0; t < 8; ++t) {
        w1s[t * 512 + tid] = W1[t * 512 + tid];
        w2s[t * 512 + tid] = W2[t * 512 + tid];
    }
    __syncthreads();
    int wv = tid >> 6, lane = tid & 63;
    float b1v = b1[lane], b2v = b2[lane];
    const int NG = (NI + NU + 7) / 8;   // node groups of 8
    for (int g = blockIdx.x; g < NG; g += gridDim.x) {
        int n = g * 8 + wv;
        bool act = n < NI + NU;
        bool isItem = n < NI;
        int nn = isItem ? n : n - NI;
        const int* rp   = isItem ? rpi : rpu;
        const int* cs   = isItem ? csri : csru;
        const float* xin  = isItem ? xi : xu;
        const float* embo = isItem ? xu : xi;
        const float* rso  = isItem ? rsdu : rsdi;
        const float* rown = isItem ? rsdi : rsdu;
        float* outp = isItem ? outi : outu;

        float sp = 0.f, ss = 0.f, sw = 0.f, rs = 0.f, dgf = 0.f, xv = 0.f;
        if (act) {
            int beg = rp[nn], end = rp[nn + 1];
            dgf = (float)(end - beg);
            rs = rown[nn];
            xv = xin[nn * 64 + lane];
            int j = beg;
            for (; j + 3 < end; j += 4) {
                int i0 = cs[j], i1 = cs[j + 1], i2 = cs[j + 2], i3 = cs[j + 3];
                float w0 = rso[i0], w1v = rso[i1], w2v = rso[i2], w3v = rso[i3];
                float v0 = embo[i0 * 64 + lane];
                float v1 = embo[i1 * 64 + lane];
                float v2 = embo[i2 * 64 + lane];
                float v3 = embo[i3 * 64 + lane];
                sp += (v0 + v1) + (v2 + v3);
                ss += w0 * v0 + w1v * v1 + w2v * v2 + w3v * v3;
                sw += (w0 + w1v) + (w2v + w3v);
            }
            for (; j < end; ++j) {
                int i0 = cs[j];
                float w0 = rso[i0];
                float v0 = embo[i0 * 64 + lane];
                sp += v0; ss += w0 * v0; sw += w0;
            }
        }
        // per-wave staging: same wave writes & reads acs[wv] -> no barrier needed
        acs[wv][lane] = rs * ss;
        acs[wv][64 + lane] = xv * sp;
        if (act) {
            float acc = 0.f;
            #pragma unroll 8
            for (int k = 0; k < 64; ++k) {
                acc += acs[wv][k] * w1s[k * 64 + lane];
                acc += acs[wv][64 + k] * w2s[k * 64 + lane];
            }
            acc += rs * sw * b1v + dgf * b2v;
            float h = acc >= 0.f ? acc : 0.2f * acc;
            float nsq = h * h;
            #pragma unroll
            for (int off = 32; off > 0; off >>= 1) nsq += __shfl_xor(nsq, off);
            float nrm = sqrtf(nsq);
            outp[nn * 64 + lane] = h / fmaxf(nrm, 1e-12f);
        }
    }
}

// ---- final gather of concatenated embeddings ----
__global__ void gather_kernel(const float* __restrict__ ue, const float* __restrict__ u1,
                              const float* __restrict__ u2, const float* __restrict__ ie,
                              const float* __restrict__ i1, const float* __restrict__ i2,
                              const int* __restrict__ users, const int* __restrict__ pos,
                              const int* __restrict__ neg, float* __restrict__ out) {
    int idx = blockIdx.x * blockDim.x + threadIdx.x;
    if (idx >= 3 * NB * 192) return;
    int which = idx / (NB * 192);
    int rem = idx - which * (NB * 192);
    int b = rem / 192, c = rem - b * 192;
    int seg = c >> 6, cc = c & 63;
    int row;
    const float* srcarr;
    if (which == 0) {
        row = users[b];
        srcarr = (seg == 0) ? ue : (seg == 1 ? u1 : u2);
    } else {
        row = (which == 1) ? pos[b] : neg[b];
        srcarr = (seg == 0) ? ie : (seg == 1 ? i1 : i2);
    }
    out[idx] = srcarr[(size_t)row * 64 + cc];
}

extern "C" void kernel_launch(void* const* d_in, const int* in_sizes, int n_in,
                              void* d_out, int out_size, void* d_ws, size_t ws_size,
                              hipStream_t stream) {
    const float* user_emb = (const float*)d_in[0];
    const float* item_emb = (const float*)d_in[1];
    const float* W1_0 = (const float*)d_in[2];
    const float* b1_0 = (const float*)d_in[3];
    const float* W2_0 = (const float*)d_in[4];
    const float* b2_0 = (const float*)d_in[5];
    const float* W1_1 = (const float*)d_in[6];
    const float* b1_1 = (const float*)d_in[7];
    const float* W2_1 = (const float*)d_in[8];
    const float* b2_1 = (const float*)d_in[9];
    const int* ei = (const int*)d_in[10];
    const int* users = (const int*)d_in[11];
    const int* pos = (const int*)d_in[12];
    const int* neg = (const int*)d_in[13];
    float* out = (float*)d_out;

    char* p = (char*)d_ws;
    int* du = (int*)p;        p += NU * 4;
    int* di = (int*)p;        p += NI * 4;
    float* rsd_u = (float*)p; p += NU * 4;
    float* rsd_i = (float*)p; p += NI * 4;
    int* psum = (int*)p;      p += (UB + IB) * 4;
    int* rp_u = (int*)p;      p += (NU + 1) * 4;
    int* rp_i = (int*)p;      p += (NI + 1) * 4;
    int* cur_u = (int*)p;     p += NU * 4;
    int* cur_i = (int*)p;     p += NI * 4;
    int* csr_u = (int*)p;     p += (size_t)NE * 4;
    int* csr_i = (int*)p;     p += (size_t)NE * 4;
    float* u1 = (float*)p;    p += (size_t)NU * 64 * 4;
    float* u2 = (float*)p;    p += (size_t)NU * 64 * 4;
    float* i1 = (float*)p;    p += (size_t)NI * 64 * 4;
    float* i2 = (float*)p;    p += (size_t)NI * 64 * 4;

    // zero the degree counters (ws is re-poisoned before every call)
    hipMemsetAsync(du, 0, (size_t)(NU + NI) * sizeof(int), stream);

    deg_kernel<<<(NE + 255) / 256, 256, 0, stream>>>(ei, du, di);
    scan1_kernel<<<UB + IB, 1024, 0, stream>>>(du, di, psum, rsd_u, rsd_i);
    scan2_kernel<<<2, 128, 0, stream>>>(psum);
    scan3_kernel<<<UB + IB, 1024, 0, stream>>>(du, di, psum, rp_u, rp_i, cur_u, cur_i);
    fill_csr_kernel<<<(NE + 255) / 256, 256, 0, stream>>>(ei, cur_u, cur_i, csr_u, csr_i);

    // ---- layer 0 ----
    gt_fused_kernel<<<1280, 512, 0, stream>>>(user_emb, item_emb, rp_u, rp_i, csr_u, csr_i,
                                              rsd_u, rsd_i, W1_0, b1_0, W2_0, b2_0, u1, i1);
    // ---- layer 1 ----
    gt_fused_kernel<<<1280, 512, 0, stream>>>(u1, i1, rp_u, rp_i, csr_u, csr_i,
                                              rsd_u, rsd_i, W1_1, b1_1, W2_1, b2_1, u2, i2);

    // ---- final gather ----
    gather_kernel<<<(3 * NB * 192 + 255) / 256, 256, 0, stream>>>(
        user_emb, u1, u2, item_emb, i1, i2, users, pos, neg, out);
}